// Round 10
// baseline (220.256 us; speedup 1.0000x reference)
//
#include <hip/hip_runtime.h>
#include <hip/hip_bf16.h>
#include <stdint.h>

typedef __attribute__((ext_vector_type(16))) float f32x16;
typedef __attribute__((ext_vector_type(8))) int i32x8;

#define M_DIM 8192
#define N_DIM 4096
#define K_DIM 4096
#define NX_INV (1.0f / 33554432.0f)
#define NW_INV (1.0f / 16777216.0f)

#define AS3(p) ((__attribute__((address_space(3))) uint32_t*)(uint32_t)(uintptr_t)(p))
#define AS1(p) ((const __attribute__((address_space(1))) uint32_t*)(uintptr_t)(p))

// ---------------- fused |x|,|w| sum reduction (one launch), fp64 atomics ----------------
__global__ void absum2_kernel(const float* __restrict__ x, const float* __restrict__ w,
                              double* __restrict__ sums) {
    bool isw = blockIdx.x >= 2048;
    const float4* src = (const float4*)(isw ? w : x);
    int n4  = isw ? (16777216 / 4) : (33554432 / 4);
    int bid = isw ? (blockIdx.x - 2048) : blockIdx.x;
    int nb  = isw ? 1024 : 2048;
    int i = bid * blockDim.x + threadIdx.x;
    int stride = nb * blockDim.x;
    float s = 0.f;
    for (; i < n4; i += stride) {
        float4 v = src[i];
        s += fabsf(v.x) + fabsf(v.y) + fabsf(v.z) + fabsf(v.w);
    }
    #pragma unroll
    for (int off = 32; off >= 1; off >>= 1) s += __shfl_down(s, off, 64);
    __shared__ float wsum[4];
    int lane = threadIdx.x & 63, wid = threadIdx.x >> 6;
    if (lane == 0) wsum[wid] = s;
    __syncthreads();
    if (threadIdx.x == 0) {
        double tot = (double)wsum[0] + (double)wsum[1] + (double)wsum[2] + (double)wsum[3];
        atomicAdd(&sums[isw ? 1 : 0], tot);
    }
}

// ---------------- fp4 e2m1 encode via pre-scaled thresholds ----------------
__device__ __forceinline__ uint32_t enc_nib_t(float x, float t0, float t1, float t2,
                                              float t3, float t4, float t5, float t6) {
    float a = fabsf(x);
    uint32_t idx;
    if (a < t3) idx = (a < t1) ? ((a < t0) ? 0u : 1u) : ((a < t2) ? 2u : 3u);
    else        idx = (a < t5) ? ((a < t4) ? 4u : 5u) : ((a < t6) ? 6u : 7u);
    return idx | ((__float_as_uint(x) >> 31) << 3);
}

// fused quant+pack for X and W (one launch); fragment-major output:
//   unit (mb, kt, l) = 16 B: row mb*32+(l&31), k in [kt*64+(l>>5)*32, +32)
//   P dword offset = ((mb*64 + kt)*64 + l)*4
__global__ void quant2_kernel(const float* __restrict__ X, const float* __restrict__ W,
                              uint32_t* __restrict__ Xp, uint32_t* __restrict__ Wp,
                              const double* __restrict__ sums) {
    __shared__ float4 tile[32 * 64];   // 32 KB, unit-swizzled: [row*64 + (col4 ^ (row&7))]

    bool isw = blockIdx.x >= 4096;
    const float* src_base = isw ? W : X;
    uint32_t* dst = isw ? Wp : Xp;
    float s = (float)(sums[isw ? 1 : 0]) * (isw ? NW_INV : NX_INV);
    int bid = isw ? (blockIdx.x - 4096) : blockIdx.x;

    float t0 = 0.25f * s, t1 = 0.75f * s, t2 = 1.25f * s, t3 = 1.75f * s;
    float t4 = 2.5f * s,  t5 = 3.5f * s,  t6 = 5.0f * s;

    int mb  = bid >> 4;
    int ktg = bid & 15;
    int t = threadIdx.x;

    {
        int row0 = t >> 6;
        int col4 = t & 63;
        const float4* src = (const float4*)(src_base + (size_t)(mb * 32 + row0) * K_DIM + ktg * 256) + col4;
        #pragma unroll
        for (int p = 0; p < 8; p++) {
            int row = p * 4 + row0;
            tile[row * 64 + (col4 ^ (row & 7))] = src[(size_t)p * 4 * (K_DIM / 4)];
        }
    }
    __syncthreads();

    int w = t >> 6;
    int l = t & 63;
    int row = l & 31;
    int ub = w * 16 + (l >> 5) * 8;
    uint32_t o[4];
    #pragma unroll
    for (int d = 0; d < 4; d++) {
        float4 f0 = tile[row * 64 + ((ub + 2 * d)     ^ (row & 7))];
        float4 f1 = tile[row * 64 + ((ub + 2 * d + 1) ^ (row & 7))];
        o[d] =  enc_nib_t(f0.x, t0,t1,t2,t3,t4,t5,t6)
             | (enc_nib_t(f0.y, t0,t1,t2,t3,t4,t5,t6) << 4)
             | (enc_nib_t(f0.z, t0,t1,t2,t3,t4,t5,t6) << 8)
             | (enc_nib_t(f0.w, t0,t1,t2,t3,t4,t5,t6) << 12)
             | (enc_nib_t(f1.x, t0,t1,t2,t3,t4,t5,t6) << 16)
             | (enc_nib_t(f1.y, t0,t1,t2,t3,t4,t5,t6) << 20)
             | (enc_nib_t(f1.z, t0,t1,t2,t3,t4,t5,t6) << 24)
             | (enc_nib_t(f1.w, t0,t1,t2,t3,t4,t5,t6) << 28);
    }
    int kt = ktg * 4 + w;
    *(uint4*)(dst + ((size_t)(mb * 64 + kt) * 64 + l) * 4) = make_uint4(o[0], o[1], o[2], o[3]);
}

// ---------------- fp4 MX GEMM: m201-style phase schedule ----------------
// 256x256 tile, 8 waves (2M x 4N), wave tile 128x64 (acc 8 x f32x16 in AGPR).
// 4-slot LDS ring (64 KB), prefetch distance 2, vmcnt(2) counted (never 0 until tail).
// Per kt: {vmcnt; bar} then ph0 {glds A(kt+2) | read A0,A1,B0,B1 | prio1 4xMFMA prio0 | bar}
//         then ph1 {glds B(kt+2) | read A2,A3 | prio1 4xMFMA prio0}.
// WAR: overwritten slot's last reads drained >= 2 barriers earlier.
#define NWG 512

__device__ __forceinline__ void glds16(const uint32_t* g, uint32_t* l) {
    __builtin_amdgcn_global_load_lds(AS1(g), AS3(l), 16, 0, 0);
}

__device__ __forceinline__ i32x8 dupfrag(uint4 u) {
    i32x8 v;
    v[0] = u.x; v[1] = u.y; v[2] = u.z; v[3] = u.w;   // fp4 consumes 4 regs; duplicate
    v[4] = u.x; v[5] = u.y; v[6] = u.z; v[7] = u.w;   // to cover either half convention
    return v;
}

#define MFMA2(VA, C0, C1) do {                                                    \
    i32x8 va_ = dupfrag(VA);                                                      \
    C0 = __builtin_amdgcn_mfma_scale_f32_32x32x64_f8f6f4(va_, vb0_, C0, 4, 4, 0, 0x7F7F7F7F, 0, 0x7F7F7F7F); \
    C1 = __builtin_amdgcn_mfma_scale_f32_32x32x64_f8f6f4(va_, vb1_, C1, 4, 4, 0, 0x7F7F7F7F, 0, 0x7F7F7F7F); \
} while (0)

#define EPI(ACC, MM, NN) do {                                                     \
    int col_ = colb + (NN) * 32;                                                  \
    float bv_ = bias[col_];                                                       \
    _Pragma("unroll")                                                             \
    for (int i = 0; i < 16; i++) {                                                \
        int row_ = rowb + (MM) * 32 + (i & 3) + ((i >> 2) << 3);                  \
        __builtin_nontemporal_store(ACC[i] * scale + bv_,                         \
                                    &C[(size_t)row_ * N_DIM + col_]);             \
    }                                                                             \
} while (0)

__global__ __launch_bounds__(512, 2)
void gemm_kernel(const uint32_t* __restrict__ Ap, const uint32_t* __restrict__ Bp,
                 const float* __restrict__ bias, float* __restrict__ C,
                 const double* __restrict__ sums) {
    __shared__ uint32_t lds[4 * 4096];       // 4 ring slots x (A 8KB | B 8KB) = 64 KB

    int bid = blockIdx.x;
    int swz = (bid & 7) * 64 + (bid >> 3);   // 512 blocks, 8 XCDs, bijective
    int bm = (swz >> 4) * 256;               // 32 m-tiles
    int bn = (swz & 15) * 256;               // 16 n-tiles

    int t = threadIdx.x;
    int lane = t & 63;
    int wid = t >> 6;
    int wm = wid >> 2;                       // 0..1: rows wm*128
    int wn = wid & 3;                        // 0..3: cols wn*64

    // staging: thread t stages 16 B of A and 16 B of B per kt (one call each)
    const uint32_t* gA = Ap + (size_t)((bm >> 5) + (t >> 6)) * 16384 + (t & 63) * 4;
    const uint32_t* gB = Bp + (size_t)((bn >> 5) + (t >> 6)) * 16384 + (t & 63) * 4;
    uint32_t* ldA = lds + t * 4;             // slot-local A region: [0, 2048) dwords
    uint32_t* ldB = lds + 2048 + t * 4;      // slot-local B region: [2048, 4096)

    // slot-local fragment read offsets (lane-linear 16B -> conflict-free)
    int oA0 = ((wm * 4 + 0) * 64 + lane) * 4;
    int oA1 = ((wm * 4 + 1) * 64 + lane) * 4;
    int oA2 = ((wm * 4 + 2) * 64 + lane) * 4;
    int oA3 = ((wm * 4 + 3) * 64 + lane) * 4;
    int oB0 = 2048 + ((wn * 2 + 0) * 64 + lane) * 4;
    int oB1 = 2048 + ((wn * 2 + 1) * 64 + lane) * 4;

    f32x16 acc00 = (f32x16)0.f, acc01 = (f32x16)0.f;
    f32x16 acc10 = (f32x16)0.f, acc11 = (f32x16)0.f;
    f32x16 acc20 = (f32x16)0.f, acc21 = (f32x16)0.f;
    f32x16 acc30 = (f32x16)0.f, acc31 = (f32x16)0.f;

    // prologue: stage tiles 0, 1
    glds16(gA + 0,   ldA + 0);
    glds16(gB + 0,   ldB + 0);
    glds16(gA + 256, ldA + 4096);
    glds16(gB + 256, ldB + 4096);

    for (int kt = 0; kt < 64; kt++) {
        // ---- K-tile boundary: tile kt landed (counted vmcnt, never 0 until tail) ----
        if (kt < 63) asm volatile("s_waitcnt vmcnt(2)" ::: "memory");
        else         asm volatile("s_waitcnt vmcnt(0)" ::: "memory");
        __builtin_amdgcn_s_barrier();

        const uint32_t* rb = lds + (kt & 3) * 4096;
        int so = ((kt + 2) & 3) * 4096;

        // ---- phase 0: stage A(kt+2) | read A0,A1,B0,B1 | MFMA m0,m1 ----
        if (kt < 62) glds16(gA + (kt + 2) * 256, ldA + so);
        uint4 rA0 = *(const uint4*)&rb[oA0];
        uint4 rA1 = *(const uint4*)&rb[oA1];
        uint4 rB0 = *(const uint4*)&rb[oB0];
        uint4 rB1 = *(const uint4*)&rb[oB1];
        i32x8 vb0_ = dupfrag(rB0);
        i32x8 vb1_ = dupfrag(rB1);
        __builtin_amdgcn_s_setprio(1);
        MFMA2(rA0, acc00, acc01);
        MFMA2(rA1, acc10, acc11);
        __builtin_amdgcn_s_setprio(0);
        __builtin_amdgcn_s_barrier();

        // ---- phase 1: stage B(kt+2) | read A2,A3 | MFMA m2,m3 ----
        if (kt < 62) glds16(gB + (kt + 2) * 256, ldB + so);
        uint4 rA2 = *(const uint4*)&rb[oA2];
        uint4 rA3 = *(const uint4*)&rb[oA3];
        __builtin_amdgcn_s_setprio(1);
        MFMA2(rA2, acc20, acc21);
        MFMA2(rA3, acc30, acc31);
        __builtin_amdgcn_s_setprio(0);
    }

    float scale = (float)((sums[0] * (1.0 / 33554432.0)) * (sums[1] * (1.0 / 16777216.0)));

    // C/D 32x32 layout: col=lane&31, row=(i&3)+8*(i>>2)+4*(lane>>5)
    int colb = bn + wn * 64 + (lane & 31);
    int rowb = bm + wm * 128 + ((lane >> 5) << 2);
    EPI(acc00, 0, 0); EPI(acc01, 0, 1);
    EPI(acc10, 1, 0); EPI(acc11, 1, 1);
    EPI(acc20, 2, 0); EPI(acc21, 2, 1);
    EPI(acc30, 3, 0); EPI(acc31, 3, 1);
}

extern "C" void kernel_launch(void* const* d_in, const int* in_sizes, int n_in,
                              void* d_out, int out_size, void* d_ws, size_t ws_size,
                              hipStream_t stream) {
    const float* x    = (const float*)d_in[0];   // [4,2048,4096]
    const float* w    = (const float*)d_in[1];   // [4096,4096]
    const float* bias = (const float*)d_in[2];   // [4096]
    float* out = (float*)d_out;                  // [4,2048,4096] fp32

    double* sums = (double*)d_ws;
    uint32_t* Xp = (uint32_t*)((char*)d_ws + 1024);   // 16 MB packed fp4, fragment-major
    uint32_t* Wp = Xp + (size_t)256 * 64 * 64 * 4;    // 8 MB

    hipMemsetAsync(d_ws, 0, 1024, stream);
    absum2_kernel<<<3072, 256, 0, stream>>>(x, w, sums);
    quant2_kernel<<<6144, 256, 0, stream>>>(x, w, Xp, Wp, sums);
    gemm_kernel<<<NWG, 512, 0, stream>>>(Xp, Wp, bias, out, sums);
}

// Round 11
// 200.903 us; speedup vs baseline: 1.0963x; 1.0963x over previous
//
#include <hip/hip_runtime.h>
#include <hip/hip_bf16.h>
#include <stdint.h>

typedef __attribute__((ext_vector_type(16))) float f32x16;
typedef __attribute__((ext_vector_type(8))) int i32x8;

#define M_DIM 8192
#define N_DIM 4096
#define K_DIM 4096
#define NX_INV (1.0f / 33554432.0f)
#define NW_INV (1.0f / 16777216.0f)

#define AS3(p) ((__attribute__((address_space(3))) uint32_t*)(uint32_t)(uintptr_t)(p))
#define AS1(p) ((const __attribute__((address_space(1))) uint32_t*)(uintptr_t)(p))

// ---------------- fused |x|,|w| sum reduction (one launch), fp64 atomics ----------------
__global__ void absum2_kernel(const float* __restrict__ x, const float* __restrict__ w,
                              double* __restrict__ sums) {
    bool isw = blockIdx.x >= 2048;
    const float4* src = (const float4*)(isw ? w : x);
    int n4  = isw ? (16777216 / 4) : (33554432 / 4);
    int bid = isw ? (blockIdx.x - 2048) : blockIdx.x;
    int nb  = isw ? 1024 : 2048;
    int i = bid * blockDim.x + threadIdx.x;
    int stride = nb * blockDim.x;
    float s = 0.f;
    for (; i < n4; i += stride) {
        float4 v = src[i];
        s += fabsf(v.x) + fabsf(v.y) + fabsf(v.z) + fabsf(v.w);
    }
    #pragma unroll
    for (int off = 32; off >= 1; off >>= 1) s += __shfl_down(s, off, 64);
    __shared__ float wsum[4];
    int lane = threadIdx.x & 63, wid = threadIdx.x >> 6;
    if (lane == 0) wsum[wid] = s;
    __syncthreads();
    if (threadIdx.x == 0) {
        double tot = (double)wsum[0] + (double)wsum[1] + (double)wsum[2] + (double)wsum[3];
        atomicAdd(&sums[isw ? 1 : 0], tot);
    }
}

// ---------------- fp4 e2m1 encode via pre-scaled thresholds ----------------
__device__ __forceinline__ uint32_t enc_nib_t(float x, float t0, float t1, float t2,
                                              float t3, float t4, float t5, float t6) {
    float a = fabsf(x);
    uint32_t idx;
    if (a < t3) idx = (a < t1) ? ((a < t0) ? 0u : 1u) : ((a < t2) ? 2u : 3u);
    else        idx = (a < t5) ? ((a < t4) ? 4u : 5u) : ((a < t6) ? 6u : 7u);
    return idx | ((__float_as_uint(x) >> 31) << 3);
}

// fused quant+pack for X and W (one launch); fragment-major output:
//   unit (mb, kt, l) = 16 B: row mb*32+(l&31), k in [kt*64+(l>>5)*32, +32)
//   P dword offset = ((mb*64 + kt)*64 + l)*4
__global__ void quant2_kernel(const float* __restrict__ X, const float* __restrict__ W,
                              uint32_t* __restrict__ Xp, uint32_t* __restrict__ Wp,
                              const double* __restrict__ sums) {
    __shared__ float4 tile[32 * 64];   // 32 KB, unit-swizzled: [row*64 + (col4 ^ (row&7))]

    bool isw = blockIdx.x >= 4096;
    const float* src_base = isw ? W : X;
    uint32_t* dst = isw ? Wp : Xp;
    float s = (float)(sums[isw ? 1 : 0]) * (isw ? NW_INV : NX_INV);
    int bid = isw ? (blockIdx.x - 4096) : blockIdx.x;

    float t0 = 0.25f * s, t1 = 0.75f * s, t2 = 1.25f * s, t3 = 1.75f * s;
    float t4 = 2.5f * s,  t5 = 3.5f * s,  t6 = 5.0f * s;

    int mb  = bid >> 4;
    int ktg = bid & 15;
    int t = threadIdx.x;

    {
        int row0 = t >> 6;
        int col4 = t & 63;
        const float4* src = (const float4*)(src_base + (size_t)(mb * 32 + row0) * K_DIM + ktg * 256) + col4;
        #pragma unroll
        for (int p = 0; p < 8; p++) {
            int row = p * 4 + row0;
            tile[row * 64 + (col4 ^ (row & 7))] = src[(size_t)p * 4 * (K_DIM / 4)];
        }
    }
    __syncthreads();

    int w = t >> 6;
    int l = t & 63;
    int row = l & 31;
    int ub = w * 16 + (l >> 5) * 8;
    uint32_t o[4];
    #pragma unroll
    for (int d = 0; d < 4; d++) {
        float4 f0 = tile[row * 64 + ((ub + 2 * d)     ^ (row & 7))];
        float4 f1 = tile[row * 64 + ((ub + 2 * d + 1) ^ (row & 7))];
        o[d] =  enc_nib_t(f0.x, t0,t1,t2,t3,t4,t5,t6)
             | (enc_nib_t(f0.y, t0,t1,t2,t3,t4,t5,t6) << 4)
             | (enc_nib_t(f0.z, t0,t1,t2,t3,t4,t5,t6) << 8)
             | (enc_nib_t(f0.w, t0,t1,t2,t3,t4,t5,t6) << 12)
             | (enc_nib_t(f1.x, t0,t1,t2,t3,t4,t5,t6) << 16)
             | (enc_nib_t(f1.y, t0,t1,t2,t3,t4,t5,t6) << 20)
             | (enc_nib_t(f1.z, t0,t1,t2,t3,t4,t5,t6) << 24)
             | (enc_nib_t(f1.w, t0,t1,t2,t3,t4,t5,t6) << 28);
    }
    int kt = ktg * 4 + w;
    *(uint4*)(dst + ((size_t)(mb * 64 + kt) * 64 + l) * 4) = make_uint4(o[0], o[1], o[2], o[3]);
}

// ---------------- fp4 MX GEMM, hybrid operand routing ----------------
// A (4x wave-shared) -> 4-slot LDS ring via global_load_lds: 32 ds_read/kt/CU.
// B (2x wave-shared) -> direct global->VGPR, depth-2 named stages (SROA-safe).
// 8 waves (2M x 4N), wave tile 128x64, acc 8 x f32x16 in AGPR, 2 waves/SIMD.
// One barrier/kt; counted vmcnt(3) = (1 glds + 2 B-loads) x distance-2 - self.
#define NWG 512

__device__ __forceinline__ void glds16(const uint32_t* g, uint32_t* l) {
    __builtin_amdgcn_global_load_lds(AS1(g), AS3(l), 16, 0, 0);
}

__device__ __forceinline__ i32x8 dupfrag(uint4 u) {
    i32x8 v;
    v[0] = u.x; v[1] = u.y; v[2] = u.z; v[3] = u.w;   // fp4 consumes 4 regs; duplicate
    v[4] = u.x; v[5] = u.y; v[6] = u.z; v[7] = u.w;   // to cover either half convention
    return v;
}

#define MFMA2(VA, C0, C1) do {                                                    \
    i32x8 va_ = dupfrag(VA);                                                      \
    C0 = __builtin_amdgcn_mfma_scale_f32_32x32x64_f8f6f4(va_, vb0_, C0, 4, 4, 0, 0x7F7F7F7F, 0, 0x7F7F7F7F); \
    C1 = __builtin_amdgcn_mfma_scale_f32_32x32x64_f8f6f4(va_, vb1_, C1, 4, 4, 0, 0x7F7F7F7F, 0, 0x7F7F7F7F); \
} while (0)

// Per K-tile step: {vmcnt; bar} -> dup B(kt) -> issue {glds A(kt+2), load B(kt+2)}
// -> ds_read A(kt) -> 8 MFMA.  WAR on A slot (kt+2)&3: tile kt-2's reads completed
// before barrier(kt-1); glds issued after barrier(kt) -> 2-barrier margin.
#define STEP(S, KT) do {                                                          \
    if ((KT) < 63) asm volatile("s_waitcnt vmcnt(3)" ::: "memory");               \
    else           asm volatile("s_waitcnt vmcnt(0)" ::: "memory");               \
    __builtin_amdgcn_s_barrier();                                                 \
    const uint32_t* rb_ = lds + (((KT) & 3) << 11);                               \
    i32x8 vb0_ = dupfrag(S##b0);                                                  \
    i32x8 vb1_ = dupfrag(S##b1);                                                  \
    if ((KT) + 2 < 64) {                                                          \
        glds16(gA + ((KT) + 2) * 256, lds + ((((KT) + 2) & 3) << 11) + t * 4);    \
        S##b0 = *(const uint4*)(pB0 + (size_t)((KT) + 2) * 256);                  \
        S##b1 = *(const uint4*)(pB1 + (size_t)((KT) + 2) * 256);                  \
    }                                                                             \
    uint4 rA0_ = *(const uint4*)&rb_[oA0];                                        \
    uint4 rA1_ = *(const uint4*)&rb_[oA1];                                        \
    uint4 rA2_ = *(const uint4*)&rb_[oA2];                                        \
    uint4 rA3_ = *(const uint4*)&rb_[oA3];                                        \
    __builtin_amdgcn_s_setprio(1);                                                \
    MFMA2(rA0_, acc00, acc01);                                                    \
    MFMA2(rA1_, acc10, acc11);                                                    \
    MFMA2(rA2_, acc20, acc21);                                                    \
    MFMA2(rA3_, acc30, acc31);                                                    \
    __builtin_amdgcn_s_setprio(0);                                                \
} while (0)

#define EPI(ACC, MM, NN) do {                                                     \
    int col_ = colb + (NN) * 32;                                                  \
    float bv_ = bias[col_];                                                       \
    _Pragma("unroll")                                                             \
    for (int i = 0; i < 16; i++) {                                                \
        int row_ = rowb + (MM) * 32 + (i & 3) + ((i >> 2) << 3);                  \
        __builtin_nontemporal_store(ACC[i] * scale + bv_,                         \
                                    &C[(size_t)row_ * N_DIM + col_]);             \
    }                                                                             \
} while (0)

__global__ __launch_bounds__(512, 2)
void gemm_kernel(const uint32_t* __restrict__ Ap, const uint32_t* __restrict__ Bp,
                 const float* __restrict__ bias, float* __restrict__ C,
                 const double* __restrict__ sums) {
    __shared__ uint32_t lds[4 * 2048];       // 4-slot A ring, 8 KB/slot = 32 KB

    int bid = blockIdx.x;
    int swz = (bid & 7) * 64 + (bid >> 3);   // 512 blocks, 8 XCDs, bijective
    int bm = (swz >> 4) * 256;               // 32 m-tiles
    int bn = (swz & 15) * 256;               // 16 n-tiles

    int t = threadIdx.x;
    int lane = t & 63;
    int wid = t >> 6;
    int wm = wid >> 2;                       // 0..1: rows wm*128
    int wn = wid & 3;                        // 0..3: cols wn*64

    // A staging: thread t stages 16 B of the 8 KB A tile per kt
    const uint32_t* gA = Ap + (size_t)((bm >> 5) + (t >> 6)) * 16384 + (t & 63) * 4;

    // B direct-load base pointers (named; fragment-major unit = 1 KB/wave-load)
    const uint32_t* pB0 = Bp + (size_t)((bn >> 5) + wn * 2 + 0) * 16384 + lane * 4;
    const uint32_t* pB1 = Bp + (size_t)((bn >> 5) + wn * 2 + 1) * 16384 + lane * 4;

    // slot-local A fragment read offsets (lane-linear 16B -> conflict-free)
    int oA0 = ((wm * 4 + 0) * 64 + lane) * 4;
    int oA1 = ((wm * 4 + 1) * 64 + lane) * 4;
    int oA2 = ((wm * 4 + 2) * 64 + lane) * 4;
    int oA3 = ((wm * 4 + 3) * 64 + lane) * 4;

    f32x16 acc00 = (f32x16)0.f, acc01 = (f32x16)0.f;
    f32x16 acc10 = (f32x16)0.f, acc11 = (f32x16)0.f;
    f32x16 acc20 = (f32x16)0.f, acc21 = (f32x16)0.f;
    f32x16 acc30 = (f32x16)0.f, acc31 = (f32x16)0.f;

    uint4 S0b0, S0b1, S1b0, S1b1;            // depth-2 named B stages

    // prologue: tiles 0 and 1 (A glds + B regs), same per-iter issue order
    glds16(gA + 0, lds + t * 4);
    S0b0 = *(const uint4*)(pB0);
    S0b1 = *(const uint4*)(pB1);
    glds16(gA + 256, lds + 2048 + t * 4);
    S1b0 = *(const uint4*)(pB0 + 256);
    S1b1 = *(const uint4*)(pB1 + 256);

    for (int kt = 0; kt < 64; kt += 2) {
        STEP(S0, kt);
        STEP(S1, kt + 1);
    }

    float scale = (float)((sums[0] * (1.0 / 33554432.0)) * (sums[1] * (1.0 / 16777216.0)));

    // C/D 32x32 layout: col=lane&31, row=(i&3)+8*(i>>2)+4*(lane>>5)
    int colb = bn + wn * 64 + (lane & 31);
    int rowb = bm + wm * 128 + ((lane >> 5) << 2);
    EPI(acc00, 0, 0); EPI(acc01, 0, 1);
    EPI(acc10, 1, 0); EPI(acc11, 1, 1);
    EPI(acc20, 2, 0); EPI(acc21, 2, 1);
    EPI(acc30, 3, 0); EPI(acc31, 3, 1);
}

extern "C" void kernel_launch(void* const* d_in, const int* in_sizes, int n_in,
                              void* d_out, int out_size, void* d_ws, size_t ws_size,
                              hipStream_t stream) {
    const float* x    = (const float*)d_in[0];   // [4,2048,4096]
    const float* w    = (const float*)d_in[1];   // [4096,4096]
    const float* bias = (const float*)d_in[2];   // [4096]
    float* out = (float*)d_out;                  // [4,2048,4096] fp32

    double* sums = (double*)d_ws;
    uint32_t* Xp = (uint32_t*)((char*)d_ws + 1024);   // 16 MB packed fp4, fragment-major
    uint32_t* Wp = Xp + (size_t)256 * 64 * 64 * 4;    // 8 MB

    hipMemsetAsync(d_ws, 0, 1024, stream);
    absum2_kernel<<<3072, 256, 0, stream>>>(x, w, sums);
    quant2_kernel<<<6144, 256, 0, stream>>>(x, w, Xp, Wp, sums);
    gemm_kernel<<<NWG, 512, 0, stream>>>(Xp, Wp, bias, out, sums);
}

// Round 12
// 189.624 us; speedup vs baseline: 1.1615x; 1.0595x over previous
//
#include <hip/hip_runtime.h>
#include <hip/hip_bf16.h>
#include <stdint.h>

typedef __attribute__((ext_vector_type(16))) float f32x16;
typedef __attribute__((ext_vector_type(8))) int i32x8;

#define M_DIM 8192
#define N_DIM 4096
#define K_DIM 4096
#define NX_INV (1.0f / 33554432.0f)
#define NW_INV (1.0f / 16777216.0f)

#define AS3(p) ((__attribute__((address_space(3))) uint32_t*)(uint32_t)(uintptr_t)(p))
#define AS1(p) ((const __attribute__((address_space(1))) uint32_t*)(uintptr_t)(p))

// ---------------- fused |x|,|w| sum reduction (one launch), fp64 atomics ----------------
__global__ void absum2_kernel(const float* __restrict__ x, const float* __restrict__ w,
                              double* __restrict__ sums) {
    bool isw = blockIdx.x >= 2048;
    const float4* src = (const float4*)(isw ? w : x);
    int n4  = isw ? (16777216 / 4) : (33554432 / 4);
    int bid = isw ? (blockIdx.x - 2048) : blockIdx.x;
    int nb  = isw ? 1024 : 2048;
    int i = bid * blockDim.x + threadIdx.x;
    int stride = nb * blockDim.x;
    float s = 0.f;
    for (; i < n4; i += stride) {
        float4 v = src[i];
        s += fabsf(v.x) + fabsf(v.y) + fabsf(v.z) + fabsf(v.w);
    }
    #pragma unroll
    for (int off = 32; off >= 1; off >>= 1) s += __shfl_down(s, off, 64);
    __shared__ float wsum[4];
    int lane = threadIdx.x & 63, wid = threadIdx.x >> 6;
    if (lane == 0) wsum[wid] = s;
    __syncthreads();
    if (threadIdx.x == 0) {
        double tot = (double)wsum[0] + (double)wsum[1] + (double)wsum[2] + (double)wsum[3];
        atomicAdd(&sums[isw ? 1 : 0], tot);
    }
}

// ---------------- fp4 e2m1 encode via pre-scaled thresholds ----------------
__device__ __forceinline__ uint32_t enc_nib_t(float x, float t0, float t1, float t2,
                                              float t3, float t4, float t5, float t6) {
    float a = fabsf(x);
    uint32_t idx;
    if (a < t3) idx = (a < t1) ? ((a < t0) ? 0u : 1u) : ((a < t2) ? 2u : 3u);
    else        idx = (a < t5) ? ((a < t4) ? 4u : 5u) : ((a < t6) ? 6u : 7u);
    return idx | ((__float_as_uint(x) >> 31) << 3);
}

// fused quant+pack for X and W (one launch); fragment-major output:
//   unit (mb, kt, l) = 16 B: row mb*32+(l&31), k in [kt*64+(l>>5)*32, +32)
//   P dword offset = ((mb*64 + kt)*64 + l)*4
__global__ void quant2_kernel(const float* __restrict__ X, const float* __restrict__ W,
                              uint32_t* __restrict__ Xp, uint32_t* __restrict__ Wp,
                              const double* __restrict__ sums) {
    __shared__ float4 tile[32 * 64];   // 32 KB, unit-swizzled: [row*64 + (col4 ^ (row&7))]

    bool isw = blockIdx.x >= 4096;
    const float* src_base = isw ? W : X;
    uint32_t* dst = isw ? Wp : Xp;
    float s = (float)(sums[isw ? 1 : 0]) * (isw ? NW_INV : NX_INV);
    int bid = isw ? (blockIdx.x - 4096) : blockIdx.x;

    float t0 = 0.25f * s, t1 = 0.75f * s, t2 = 1.25f * s, t3 = 1.75f * s;
    float t4 = 2.5f * s,  t5 = 3.5f * s,  t6 = 5.0f * s;

    int mb  = bid >> 4;
    int ktg = bid & 15;
    int t = threadIdx.x;

    {
        int row0 = t >> 6;
        int col4 = t & 63;
        const float4* src = (const float4*)(src_base + (size_t)(mb * 32 + row0) * K_DIM + ktg * 256) + col4;
        #pragma unroll
        for (int p = 0; p < 8; p++) {
            int row = p * 4 + row0;
            tile[row * 64 + (col4 ^ (row & 7))] = src[(size_t)p * 4 * (K_DIM / 4)];
        }
    }
    __syncthreads();

    int w = t >> 6;
    int l = t & 63;
    int row = l & 31;
    int ub = w * 16 + (l >> 5) * 8;
    uint32_t o[4];
    #pragma unroll
    for (int d = 0; d < 4; d++) {
        float4 f0 = tile[row * 64 + ((ub + 2 * d)     ^ (row & 7))];
        float4 f1 = tile[row * 64 + ((ub + 2 * d + 1) ^ (row & 7))];
        o[d] =  enc_nib_t(f0.x, t0,t1,t2,t3,t4,t5,t6)
             | (enc_nib_t(f0.y, t0,t1,t2,t3,t4,t5,t6) << 4)
             | (enc_nib_t(f0.z, t0,t1,t2,t3,t4,t5,t6) << 8)
             | (enc_nib_t(f0.w, t0,t1,t2,t3,t4,t5,t6) << 12)
             | (enc_nib_t(f1.x, t0,t1,t2,t3,t4,t5,t6) << 16)
             | (enc_nib_t(f1.y, t0,t1,t2,t3,t4,t5,t6) << 20)
             | (enc_nib_t(f1.z, t0,t1,t2,t3,t4,t5,t6) << 24)
             | (enc_nib_t(f1.w, t0,t1,t2,t3,t4,t5,t6) << 28);
    }
    int kt = ktg * 4 + w;
    *(uint4*)(dst + ((size_t)(mb * 64 + kt) * 64 + l) * 4) = make_uint4(o[0], o[1], o[2], o[3]);
}

// ---------------- fp4 MX GEMM: small-acc / high-residency ----------------
// 256x256 tile, 16 waves (4M x 4N), wave tile 64x64: acc = 4 x f32x16 = 64 AGPR
// -> total regs ~150/wave -> 3 waves/SIMD (vs <=2 in every prior structure).
// 4-slot LDS ring (64 KB); 1 glds16/thread/kt (A-half: t<512, B-half: t>=512);
// 4 ds_read_b128 + 4 MFMA per wave per kt; 1 barrier + counted vmcnt(1)/kt.
#define NWG 512

__device__ __forceinline__ void glds16(const uint32_t* g, uint32_t* l) {
    __builtin_amdgcn_global_load_lds(AS1(g), AS3(l), 16, 0, 0);
}

__device__ __forceinline__ i32x8 dupfrag(uint4 u) {
    i32x8 v;
    v[0] = u.x; v[1] = u.y; v[2] = u.z; v[3] = u.w;   // fp4 consumes 4 regs; duplicate
    v[4] = u.x; v[5] = u.y; v[6] = u.z; v[7] = u.w;   // to cover either half convention
    return v;
}

#define MFMA(VA, VB, CC) \
    CC = __builtin_amdgcn_mfma_scale_f32_32x32x64_f8f6f4(VA, VB, CC, 4, 4, 0, 0x7F7F7F7F, 0, 0x7F7F7F7F)

#define EPI(ACC, MM, NN) do {                                                     \
    int col_ = colb + (NN) * 32;                                                  \
    float bv_ = bias[col_];                                                       \
    _Pragma("unroll")                                                             \
    for (int i = 0; i < 16; i++) {                                                \
        int row_ = rowb + (MM) * 32 + (i & 3) + ((i >> 2) << 3);                  \
        __builtin_nontemporal_store(ACC[i] * scale + bv_,                         \
                                    &C[(size_t)row_ * N_DIM + col_]);             \
    }                                                                             \
} while (0)

__global__ __launch_bounds__(1024, 3)
void gemm_kernel(const uint32_t* __restrict__ Ap, const uint32_t* __restrict__ Bp,
                 const float* __restrict__ bias, float* __restrict__ C,
                 const double* __restrict__ sums) {
    __shared__ uint32_t lds[4 * 4096];       // 4 ring slots x (A 8KB | B 8KB) = 64 KB

    int bid = blockIdx.x;
    int swz = (bid & 7) * 64 + (bid >> 3);   // 512 blocks, 8 XCDs, bijective
    int bm = (swz >> 4) * 256;               // 32 m-tiles
    int bn = (swz & 15) * 256;               // 16 n-tiles

    int t = threadIdx.x;
    int lane = t & 63;
    int wid = t >> 6;                        // 0..15
    int wm4 = wid >> 2;                      // 0..3: rows wm4*64
    int wn4 = wid & 3;                       // 0..3: cols wn4*64

    // staging: threads 0-511 stage the 8 KB A tile, 512-1023 the 8 KB B tile
    const uint32_t* gsrc = (t < 512)
        ? Ap + (size_t)((bm >> 5) + (t >> 6)) * 16384 + (t & 63) * 4
        : Bp + (size_t)((bn >> 5) + ((t >> 6) - 8)) * 16384 + (t & 63) * 4;
    int ldst = t * 4;                        // A lands in [0,2048), B in [2048,4096) dwords

    // slot-local fragment read offsets (lane-linear 16B -> conflict-free)
    int oA0 = (2 * wm4 + 0) * 256 + lane * 4;
    int oA1 = (2 * wm4 + 1) * 256 + lane * 4;
    int oB0 = 2048 + (2 * wn4 + 0) * 256 + lane * 4;
    int oB1 = 2048 + (2 * wn4 + 1) * 256 + lane * 4;

    f32x16 acc00 = (f32x16)0.f, acc01 = (f32x16)0.f;
    f32x16 acc10 = (f32x16)0.f, acc11 = (f32x16)0.f;

    // prologue: stage K-tiles 0, 1
    glds16(gsrc + 0,   lds + ldst);
    glds16(gsrc + 256, lds + 4096 + ldst);

    for (int kt = 0; kt < 64; kt++) {
        // tile kt landed; tile kt+1 stays in flight (counted vmcnt, 0 only at tail)
        if (kt < 63) asm volatile("s_waitcnt vmcnt(1)" ::: "memory");
        else         asm volatile("s_waitcnt vmcnt(0)" ::: "memory");
        __builtin_amdgcn_s_barrier();

        const uint32_t* rb = lds + (kt & 3) * 4096;
        if (kt < 62) glds16(gsrc + (kt + 2) * 256, lds + ((kt + 2) & 3) * 4096 + ldst);

        uint4 rA0 = *(const uint4*)&rb[oA0];
        uint4 rA1 = *(const uint4*)&rb[oA1];
        uint4 rB0 = *(const uint4*)&rb[oB0];
        uint4 rB1 = *(const uint4*)&rb[oB1];
        i32x8 vb0 = dupfrag(rB0);
        i32x8 vb1 = dupfrag(rB1);
        i32x8 va0 = dupfrag(rA0);
        MFMA(va0, vb0, acc00);
        MFMA(va0, vb1, acc01);
        i32x8 va1 = dupfrag(rA1);
        MFMA(va1, vb0, acc10);
        MFMA(va1, vb1, acc11);
    }

    float scale = (float)((sums[0] * (1.0 / 33554432.0)) * (sums[1] * (1.0 / 16777216.0)));

    // C/D 32x32 layout: col=lane&31, row=(i&3)+8*(i>>2)+4*(lane>>5)
    int colb = bn + wn4 * 64 + (lane & 31);
    int rowb = bm + wm4 * 64 + ((lane >> 5) << 2);
    EPI(acc00, 0, 0); EPI(acc01, 0, 1);
    EPI(acc10, 1, 0); EPI(acc11, 1, 1);
}

extern "C" void kernel_launch(void* const* d_in, const int* in_sizes, int n_in,
                              void* d_out, int out_size, void* d_ws, size_t ws_size,
                              hipStream_t stream) {
    const float* x    = (const float*)d_in[0];   // [4,2048,4096]
    const float* w    = (const float*)d_in[1];   // [4096,4096]
    const float* bias = (const float*)d_in[2];   // [4096]
    float* out = (float*)d_out;                  // [4,2048,4096] fp32

    double* sums = (double*)d_ws;
    uint32_t* Xp = (uint32_t*)((char*)d_ws + 1024);   // 16 MB packed fp4, fragment-major
    uint32_t* Wp = Xp + (size_t)256 * 64 * 64 * 4;    // 8 MB

    hipMemsetAsync(d_ws, 0, 1024, stream);
    absum2_kernel<<<3072, 256, 0, stream>>>(x, w, sums);
    quant2_kernel<<<6144, 256, 0, stream>>>(x, w, Xp, Wp, sums);
    gemm_kernel<<<NWG, 1024, 0, stream>>>(Xp, Wp, bias, out, sums);
}